// Round 4
// baseline (821.625 us; speedup 1.0000x reference)
//
#include <hip/hip_runtime.h>

typedef __attribute__((ext_vector_type(8))) short bf16x8;    // 8 bf16 (4 VGPRs)
typedef __attribute__((ext_vector_type(16))) float f32x16;   // 32x32 MFMA C/D
typedef __attribute__((ext_vector_type(4))) float f32x4;
typedef __attribute__((ext_vector_type(4))) float f4;
typedef __attribute__((ext_vector_type(2))) unsigned int u32x2;
typedef __attribute__((ext_vector_type(4))) unsigned int u32x4;

#define HW   16384   // 128*128
#define FDIM 512
#define LSTR 40      // LDS row stride in ushorts (80 B, 16B-aligned, conflict-benign)
#define LBUF 5120    // 128*LSTR ushorts per buffer

// LDS-only barrier: drains ds ops, leaves global prefetches in flight (no vmcnt(0))
#define BARRIER() asm volatile("s_waitcnt lgkmcnt(0)\n\ts_barrier" ::: "memory")

__device__ __forceinline__ unsigned pkhi(float a, float b) {
    return __builtin_amdgcn_perm(__builtin_bit_cast(unsigned int, b),
                                 __builtin_bit_cast(unsigned int, a),
                                 0x07060302u);
}
__device__ __forceinline__ float trhi(float a) {
    return __builtin_bit_cast(float, __builtin_bit_cast(unsigned int, a) & 0xFFFF0000u);
}
__device__ __forceinline__ unsigned pklo(float a, float b) {
    return pkhi(a - trhi(a), b - trhi(b));
}

// Prologue: W[e,c,f] fp32 -> W'[kchunk 0..63][n 0..1023][8] bf16 hi/lo, n = c*16+e.
__global__ __launch_bounds__(256) void conv_w(const float* __restrict__ wts,
                                              unsigned short* __restrict__ wh,
                                              unsigned short* __restrict__ wl) {
    const int tid = blockIdx.x * 256 + threadIdx.x;
    const int n  = tid & 1023;
    const int kc = tid >> 10;
    const float* src = wts + (size_t)((n & 15) * 64 + (n >> 4)) * FDIM + kc * 8;
    f4 a = *(const f4*)src, b = *(const f4*)(src + 4);
    u32x4 h = { pkhi(a[0], a[1]), pkhi(a[2], a[3]), pkhi(b[0], b[1]), pkhi(b[2], b[3]) };
    u32x4 l = { pklo(a[0], a[1]), pklo(a[2], a[3]), pklo(b[0], b[1]), pklo(b[2], b[3]) };
    size_t off = ((size_t)kc * 1024 + n) * 8;
    *(u32x4*)(wh + off) = h;
    *(u32x4*)(wl + off) = l;
}

__device__ __forceinline__ void packA(const f4* av, unsigned short* aH, unsigned short* aL) {
    #pragma unroll
    for (int j = 0; j < 4; ++j) {
        float a0 = av[0][j], a1 = av[1][j], a2 = av[2][j], a3 = av[3][j];
        u32x2 h, l;
        h[0] = pkhi(a0, a1); h[1] = pkhi(a2, a3);
        l[0] = pklo(a0, a1); l[1] = pklo(a2, a3);
        *(u32x2*)(aH + j * LSTR) = h;
        *(u32x2*)(aL + j * LSTR) = l;
    }
}

#define MFMA_CELL(jn, FH, FL)                                                              \
    acc[0][jn] = __builtin_amdgcn_mfma_f32_32x32x16_bf16(FH[0], cbh, acc[0][jn], 0, 0, 0); \
    acc[1][jn] = __builtin_amdgcn_mfma_f32_32x32x16_bf16(FH[1], cbh, acc[1][jn], 0, 0, 0); \
    acc[0][jn] = __builtin_amdgcn_mfma_f32_32x32x16_bf16(FH[0], cbl, acc[0][jn], 0, 0, 0); \
    acc[1][jn] = __builtin_amdgcn_mfma_f32_32x32x16_bf16(FH[1], cbl, acc[1][jn], 0, 0, 0); \
    acc[0][jn] = __builtin_amdgcn_mfma_f32_32x32x16_bf16(FL[0], cbh, acc[0][jn], 0, 0, 0); \
    acc[1][jn] = __builtin_amdgcn_mfma_f32_32x32x16_bf16(FL[1], cbh, acc[1][jn], 0, 0, 0);

// Main: C[m=pixel, n=c*16+e] = feat . W  (32x32x16 MFMA, 3-product bf16 hi/lo);
// epilogue: out[b,c,h,w] = exp(-3.125 * sum_e (C - cent)^2).
__global__ __launch_bounds__(256, 4) void duq_main(
    const float* __restrict__ feat,
    const unsigned short* __restrict__ wh,
    const unsigned short* __restrict__ wl,
    const float* __restrict__ m_in,
    const float* __restrict__ n_in,
    float* __restrict__ out)
{
    __shared__ __align__(16) unsigned short Ah[2 * LBUF];   // double-buffered A hi
    __shared__ __align__(16) unsigned short Al[2 * LBUF];   // double-buffered A lo

    const int t  = threadIdx.x;
    const int bx = blockIdx.x;
    const int nb = bx & 7;
    const int mb = bx >> 3;
    const int bidx = mb >> 7;
    const int hw0  = (mb & 127) << 7;

    // A staging: thread covers 4(f) x 4(p)
    const int fb = t & 7;
    const int pb = t >> 3;
    const float* ap = feat + (size_t)bidx * (FDIM * HW) + (size_t)(fb * 4) * HW + (hw0 + pb * 4);
    const int awo = (pb * 4) * LSTR + fb * 4;

    const int lane = t & 63;
    const int wv = t >> 6;
    const int wm = wv >> 1, wn = wv & 1;       // 2x2 waves, 64x64 each
    const int lane32 = lane & 31;
    const int khalf  = lane >> 5;

    // A-frag base: row = wm*64 + im*32 + lane32, col = ksub*16 + khalf*8
    const int aro = (wm * 64 + lane32) * LSTR + khalf * 8;

    // B-frag base: frag(kt,ksub,jn) at +kt*32768 + ksub*16384 + jn*256 (ushorts)
    const int n0 = nb * 128 + wn * 64 + lane32;
    const size_t bo0 = ((size_t)khalf * 1024 + n0) * 8;
    const unsigned short* bgh = wh + bo0;
    const unsigned short* bgl = wl + bo0;

    f32x16 acc[2][2] = {};   // [im][jn]

    f4 av[4];
    #pragma unroll
    for (int i = 0; i < 4; ++i) av[i] = *(const f4*)(ap + (size_t)i * HW);
    bf16x8 cbh = *(const bf16x8*)(bgh);        // cell (kt0, j0, k0)
    bf16x8 cbl = *(const bf16x8*)(bgl);

    packA(av, Ah + awo, Al + awo);             // tile 0 -> buf0
    ap += 32 * HW;
    #pragma unroll
    for (int i = 0; i < 4; ++i) av[i] = *(const f4*)(ap + (size_t)i * HW);   // tile 1
    BARRIER();

    for (int kt = 0; kt < 16; ++kt) {
        const int rb = (kt & 1) ? LBUF : 0;
        const int wb = LBUF - rb;

        // ksub0 A-frags from read buffer
        bf16x8 fh0[2], fl0[2];
        #pragma unroll
        for (int im = 0; im < 2; ++im) {
            fh0[im] = *(const bf16x8*)(&Ah[rb + aro + im * 1280]);
            fl0[im] = *(const bf16x8*)(&Al[rb + aro + im * 1280]);
        }
        // stage tile kt+1 into write buffer (VALU fills the ds_read shadow)
        if (kt < 15) packA(av, Ah + wb + awo, Al + wb + awo);
        // global prefetch tile kt+2
        if (kt < 14) {
            ap += 32 * HW;
            #pragma unroll
            for (int i = 0; i < 4; ++i) av[i] = *(const f4*)(ap + (size_t)i * HW);
        }

        const size_t kto = (size_t)kt * 32768;
        // ---- cell (j0,k0); prefetch (j1,k0)
        bf16x8 nh = *(const bf16x8*)(bgh + kto + 256);
        bf16x8 nl = *(const bf16x8*)(bgl + kto + 256);
        MFMA_CELL(0, fh0, fl0);
        cbh = nh; cbl = nl;
        // ---- cell (j1,k0); prefetch (j0,k1); load ksub1 A-frags (fh0 dies here)
        nh = *(const bf16x8*)(bgh + kto + 16384);
        nl = *(const bf16x8*)(bgl + kto + 16384);
        bf16x8 fh1[2], fl1[2];
        #pragma unroll
        for (int im = 0; im < 2; ++im) {
            fh1[im] = *(const bf16x8*)(&Ah[rb + aro + im * 1280 + 16]);
            fl1[im] = *(const bf16x8*)(&Al[rb + aro + im * 1280 + 16]);
        }
        MFMA_CELL(1, fh0, fl0);
        cbh = nh; cbl = nl;
        // ---- cell (j0,k1); prefetch (j1,k1)
        nh = *(const bf16x8*)(bgh + kto + 16640);
        nl = *(const bf16x8*)(bgl + kto + 16640);
        MFMA_CELL(0, fh1, fl1);
        cbh = nh; cbl = nl;
        // ---- cell (j1,k1); prefetch next kt (j0,k0) (tail read covered by ws slack)
        nh = *(const bf16x8*)(bgh + kto + 32768);
        nl = *(const bf16x8*)(bgl + kto + 32768);
        MFMA_CELL(1, fh1, fl1);
        cbh = nh; cbl = nl;

        if (kt < 15) BARRIER();
    }

    // ---- epilogue: 32x32 C layout col=lane&31, row=(r&3)+8*(r>>2)+4*(lane>>5)
    const int l16  = lane & 15;
    const int half = lane >> 5;
    #pragma unroll
    for (int im = 0; im < 2; ++im) {
        #pragma unroll
        for (int jn = 0; jn < 2; ++jn) {
            const int c = nb * 8 + wn * 4 + jn * 2 + ((lane >> 4) & 1);
            const float cent = m_in[l16 * 64 + c] / n_in[c];
            float s[16];
            #pragma unroll
            for (int r = 0; r < 16; ++r) {
                float d = acc[im][jn][r] - cent;
                s[r] = d * d;
            }
            #pragma unroll
            for (int r = 0; r < 16; ++r) {
                #pragma unroll
                for (int msk = 1; msk < 16; msk <<= 1)
                    s[r] += __shfl_xor(s[r], msk, 64);
            }
            if (l16 < 4) {               // lane q of each 16-group stores rows 8q+4*half..+3
                const int q = l16;
                f4 o;
                #pragma unroll
                for (int z = 0; z < 4; ++z) o[z] = __expf(s[4 * q + z] * -3.125f);
                size_t off = ((size_t)(bidx * 64 + c)) * HW
                           + (size_t)(hw0 + wm * 64 + im * 32 + 8 * q + 4 * half);
                *(f4*)(out + off) = o;
            }
        }
    }
}

// Fallback (R2 kernel) if ws too small for W'.
__global__ __launch_bounds__(256) void duq_fallback(
    const float* __restrict__ feat, const float* __restrict__ wts,
    const float* __restrict__ m_in, const float* __restrict__ n_in,
    float* __restrict__ out)
{
    __shared__ __align__(16) unsigned short FAh[128 * 40];
    __shared__ __align__(16) unsigned short FAl[128 * 40];
    __shared__ __align__(16) unsigned short FBh[128 * 40];
    __shared__ __align__(16) unsigned short FBl[128 * 40];

    const int t  = threadIdx.x;
    const int bx = blockIdx.x;
    const int nb = bx & 7;
    const int mb = bx >> 3;
    const int bidx = mb >> 7;
    const int hw0  = (mb & 127) << 7;

    const int fb = t & 7;
    const int pb = t >> 3;
    const float* ap = feat + (size_t)bidx * (FDIM * HW) + (size_t)(fb * 4) * HW + (hw0 + pb * 4);

    const int bn  = t >> 1;
    const int bh_ = t & 1;
    const int ng  = nb * 128 + bn;
    const float* bp = wts + (size_t)((ng & 15) * 64 + (ng >> 4)) * FDIM + bh_ * 16;

    unsigned short* awH = &FAh[(pb * 4) * 40 + fb * 4];
    unsigned short* awL = &FAl[(pb * 4) * 40 + fb * 4];
    unsigned short* bwH = &FBh[bn * 40 + bh_ * 16];
    unsigned short* bwL = &FBl[bn * 40 + bh_ * 16];

    const int lane = t & 63;
    const int wv = t >> 6;
    const int wm = wv >> 1, wn = wv & 1;
    const int l16 = lane & 15, qd = lane >> 4;

    const unsigned short* arH = &FAh[(wm * 64 + l16) * 40 + qd * 8];
    const unsigned short* arL = &FAl[(wm * 64 + l16) * 40 + qd * 8];
    const unsigned short* brH = &FBh[(wn * 64 + l16) * 40 + qd * 8];
    const unsigned short* brL = &FBl[(wn * 64 + l16) * 40 + qd * 8];

    f32x4 acc[4][4] = {};

    f4 av[4], bv[4];
    #pragma unroll
    for (int i = 0; i < 4; ++i) av[i] = *(const f4*)(ap + (size_t)i * HW);
    #pragma unroll
    for (int q = 0; q < 4; ++q) bv[q] = *(const f4*)(bp + q * 4);

    for (int kt = 0; kt < 16; ++kt) {
        __syncthreads();
        #pragma unroll
        for (int j = 0; j < 4; ++j) {
            float a0 = av[0][j], a1 = av[1][j], a2 = av[2][j], a3 = av[3][j];
            u32x2 h, l;
            h[0] = pkhi(a0, a1); h[1] = pkhi(a2, a3);
            l[0] = pklo(a0, a1); l[1] = pklo(a2, a3);
            *(u32x2*)(awH + j * 40) = h;
            *(u32x2*)(awL + j * 40) = l;
        }
        {
            u32x4 h0 = { pkhi(bv[0][0], bv[0][1]), pkhi(bv[0][2], bv[0][3]),
                         pkhi(bv[1][0], bv[1][1]), pkhi(bv[1][2], bv[1][3]) };
            u32x4 h1 = { pkhi(bv[2][0], bv[2][1]), pkhi(bv[2][2], bv[2][3]),
                         pkhi(bv[3][0], bv[3][1]), pkhi(bv[3][2], bv[3][3]) };
            u32x4 l0 = { pklo(bv[0][0], bv[0][1]), pklo(bv[0][2], bv[0][3]),
                         pklo(bv[1][0], bv[1][1]), pklo(bv[1][2], bv[1][3]) };
            u32x4 l1 = { pklo(bv[2][0], bv[2][1]), pklo(bv[2][2], bv[2][3]),
                         pklo(bv[3][0], bv[3][1]), pklo(bv[3][2], bv[3][3]) };
            *(u32x4*)(bwH)     = h0;  *(u32x4*)(bwH + 8) = h1;
            *(u32x4*)(bwL)     = l0;  *(u32x4*)(bwL + 8) = l1;
        }
        __syncthreads();

        if (kt < 15) {
            ap += 32 * HW;
            bp += 32;
            #pragma unroll
            for (int i = 0; i < 4; ++i) av[i] = *(const f4*)(ap + (size_t)i * HW);
            #pragma unroll
            for (int q = 0; q < 4; ++q) bv[q] = *(const f4*)(bp + q * 4);
        }

        bf16x8 fah[4], fal[4];
        #pragma unroll
        for (int i = 0; i < 4; ++i) {
            fah[i] = *(const bf16x8*)(arH + i * 640);
            fal[i] = *(const bf16x8*)(arL + i * 640);
        }
        #pragma unroll
        for (int j = 0; j < 4; ++j) {
            bf16x8 fbh = *(const bf16x8*)(brH + j * 640);
            bf16x8 fbl = *(const bf16x8*)(brL + j * 640);
            #pragma unroll
            for (int i = 0; i < 4; ++i) {
                acc[i][j] = __builtin_amdgcn_mfma_f32_16x16x32_bf16(fah[i], fbh, acc[i][j], 0, 0, 0);
                acc[i][j] = __builtin_amdgcn_mfma_f32_16x16x32_bf16(fah[i], fbl, acc[i][j], 0, 0, 0);
                acc[i][j] = __builtin_amdgcn_mfma_f32_16x16x32_bf16(fal[i], fbh, acc[i][j], 0, 0, 0);
            }
        }
    }

    float centv[4];
    #pragma unroll
    for (int j = 0; j < 4; ++j) {
        int cj = nb * 8 + wn * 4 + j;
        centv[j] = m_in[l16 * 64 + cj] / n_in[cj];
    }
    #pragma unroll
    for (int i = 0; i < 4; ++i) {
        #pragma unroll
        for (int j = 0; j < 4; ++j) {
            float s0 = acc[i][j][0] - centv[j]; s0 *= s0;
            float s1 = acc[i][j][1] - centv[j]; s1 *= s1;
            float s2 = acc[i][j][2] - centv[j]; s2 *= s2;
            float s3 = acc[i][j][3] - centv[j]; s3 *= s3;
            #pragma unroll
            for (int msk = 1; msk < 16; msk <<= 1) {
                s0 += __shfl_xor(s0, msk, 64);
                s1 += __shfl_xor(s1, msk, 64);
                s2 += __shfl_xor(s2, msk, 64);
                s3 += __shfl_xor(s3, msk, 64);
            }
            if (l16 == 0) {
                int cj = nb * 8 + wn * 4 + j;
                f4 o;
                o[0] = __expf(s0 * -3.125f);
                o[1] = __expf(s1 * -3.125f);
                o[2] = __expf(s2 * -3.125f);
                o[3] = __expf(s3 * -3.125f);
                size_t off = ((size_t)(bidx * 64 + cj)) * HW
                           + (size_t)(hw0 + wm * 64 + i * 16 + qd * 4);
                *(f4*)(out + off) = o;
            }
        }
    }
}

extern "C" void kernel_launch(void* const* d_in, const int* in_sizes, int n_in,
                              void* d_out, int out_size, void* d_ws, size_t ws_size,
                              hipStream_t stream) {
    const float* feat = (const float*)d_in[0];
    const float* wts  = (const float*)d_in[1];
    const float* mbuf = (const float*)d_in[2];
    const float* nbuf = (const float*)d_in[3];
    float* out = (float*)d_out;

    if (ws_size >= (size_t)(2 * 1024 * 1024 + 128 * 1024)) {
        unsigned short* wh = (unsigned short*)d_ws;
        unsigned short* wl = wh + 512 * 1024;
        conv_w<<<dim3(256), dim3(256), 0, stream>>>(wts, wh, wl);
        duq_main<<<dim3(1024 * 8), dim3(256), 0, stream>>>(feat, wh, wl, mbuf, nbuf, out);
    } else {
        duq_fallback<<<dim3(1024 * 8), dim3(256), 0, stream>>>(feat, wts, mbuf, nbuf, out);
    }
}